// Round 1
// 416.437 us; speedup vs baseline: 1.1690x; 1.1690x over previous
//
#include <hip/hip_runtime.h>
#include <hip/hip_bf16.h>
#include <math.h>

#define HID 64
#define KT 64

#define NBBITS 10
#define NBSZ 1024       // nodes per bucket
#define P1_BMAX 128     // max buckets supported by bucketize LDS
#define P1_CH 4096      // edges per bucketize block
#define P1_CAP 96       // LDS list capacity per bucket (mean ~42 at E/N=16)

static inline size_t align256(size_t x) { return (x + 255) & ~(size_t)255; }

__device__ inline void gld_lds16(const float* g, float* lds) {
  __builtin_amdgcn_global_load_lds((const __attribute__((address_space(1))) void*)g,
                                   (__attribute__((address_space(3))) void*)lds, 16, 0, 0);
}

// ---------- fallback-path degree count ----------

__global__ void count_dst_kernel(const int* __restrict__ dst, int* __restrict__ cnt, int E) {
  int e = blockIdx.x * blockDim.x + threadIdx.x;
  if (e < E) atomicAdd(&cnt[dst[e]], 1);
}

__global__ void dinv_kernel(const int* __restrict__ cnt, float* __restrict__ dinv, int N) {
  int i = blockIdx.x * blockDim.x + threadIdx.x;
  if (i < N) dinv[i] = rsqrtf((float)(cnt[i] + 1));  // +1 self-loop
}

// ---------- CSR path: 2-pass bucket sort (replaces count+scan+scatter) ----------

// per-bucket edge counts, LDS-aggregated (tiny atomic traffic to global)
__global__ void bucket_count_kernel(const int* __restrict__ dst, int* __restrict__ bcnt,
                                    int E, int B) {
  __shared__ int sh[1024];
  for (int i = threadIdx.x; i < B; i += blockDim.x) sh[i] = 0;
  __syncthreads();
  for (int e = blockIdx.x * blockDim.x + threadIdx.x; e < E; e += gridDim.x * blockDim.x)
    atomicAdd(&sh[dst[e] >> NBBITS], 1);
  __syncthreads();
  for (int i = threadIdx.x; i < B; i += blockDim.x) {
    int v = sh[i];
    if (v) atomicAdd(&bcnt[i], v);
  }
}

// exclusive scan of bucket counts -> bbase[0..B], init per-bucket cursors
__global__ __launch_bounds__(1024) void bucket_scan_kernel(const int* __restrict__ bcnt,
                                                           int* __restrict__ bbase,
                                                           int* __restrict__ gcur, int B) {
  __shared__ int sh[1024];
  int t = threadIdx.x;
  int v = (t < B) ? bcnt[t] : 0;
  sh[t] = v;
  __syncthreads();
  for (int off = 1; off < 1024; off <<= 1) {
    int u = (t >= off) ? sh[t - off] : 0;
    __syncthreads();
    sh[t] += u;
    __syncthreads();
  }
  if (t < B) {
    int ex = sh[t] - v;
    bbase[t] = ex;
    gcur[t] = ex;
  }
  if (t == 1023) bbase[B] = sh[1023];
}

// pass 1: partition edges into bucket regions with wave-coalesced chunk flushes.
// entry packed to 4B: (src<<NBBITS) | (dst & (NBSZ-1))  [requires N < 2^(31-NBBITS)]
__global__ __launch_bounds__(256) void bucketize_kernel(const int* __restrict__ src,
                                                        const int* __restrict__ dst,
                                                        int* __restrict__ gcur,
                                                        int* __restrict__ ebuck, int E) {
  __shared__ int cnt[P1_BMAX];
  __shared__ int lists[P1_BMAX * P1_CAP];
  int t = threadIdx.x;
  for (int i = t; i < P1_BMAX; i += 256) cnt[i] = 0;
  __syncthreads();
  int base_e = blockIdx.x * P1_CH;
#pragma unroll
  for (int u = 0; u < P1_CH / 256; ++u) {
    int e = base_e + u * 256 + t;
    if (e < E) {
      int s = src[e], d = dst[e];
      int bk = d >> NBBITS;
      int packed = (s << NBBITS) | (d & (NBSZ - 1));
      int p = atomicAdd(&cnt[bk], 1);
      if (p < P1_CAP) {
        lists[bk * P1_CAP + p] = packed;
      } else {  // statistical overflow: direct (rare) scattered write, still correct
        int gp = atomicAdd(&gcur[bk], 1);
        ebuck[gp] = packed;
      }
    }
  }
  __syncthreads();
  // flush: wave w owns buckets [w*32, w*32+32); lanes<32 pre-issue the 32 cursor
  // atomics in parallel, then each bucket chunk is written wave-coalesced.
  int w = t >> 6, lane = t & 63;
  int bk = w * 32 + (lane & 31);
  int c = min(cnt[bk], P1_CAP);
  int mybase = 0;
  if (lane < 32 && c > 0) mybase = atomicAdd(&gcur[bk], c);
#pragma unroll 1
  for (int i = 0; i < 32; ++i) {
    int cb = __shfl(c, i);
    if (cb == 0) continue;
    int gb = __shfl(mybase, i);
    int bb = w * 32 + i;
    if (lane < cb) ebuck[gb + lane] = lists[bb * P1_CAP + lane];
    if (cb > 64 && lane < cb - 64) ebuck[gb + 64 + lane] = lists[bb * P1_CAP + 64 + lane];
  }
}

// pass 2: one block owns one bucket exclusively. Counts per node in LDS,
// block-scan -> rowptr written directly; scatter writes confined to this
// block's contiguous region => its XCD's L2 accumulates full lines (no
// partial-line write amplification).
__global__ __launch_bounds__(1024) void bucket_sort_kernel(const int* __restrict__ ebuck,
                                                           const int* __restrict__ bbase,
                                                           int* __restrict__ rowptr,
                                                           int* __restrict__ epack,
                                                           int N, int B, int E) {
  __shared__ int lcnt[NBSZ];
  __shared__ int lcur[NBSZ];
  int b = blockIdx.x;
  int t = threadIdx.x;
  int n0 = b << NBBITS;
  lcnt[t] = 0;
  __syncthreads();
  int e0 = bbase[b], e1 = bbase[b + 1];
  for (int i = e0 + t; i < e1; i += 1024) atomicAdd(&lcnt[ebuck[i] & (NBSZ - 1)], 1);
  __syncthreads();
  int v = lcnt[t];
  for (int off = 1; off < 1024; off <<= 1) {
    int u = (t >= off) ? lcnt[t - off] : 0;
    __syncthreads();
    lcnt[t] += u;
    __syncthreads();
  }
  int ex = lcnt[t] - v;  // local exclusive
  int node = n0 + t;
  if (node < N) rowptr[node] = e0 + ex;
  if (b == B - 1 && t == 0) rowptr[N] = E;
  lcur[t] = e0 + ex;
  __syncthreads();
  for (int i = e0 + t; i < e1; i += 1024) {
    int pv = ebuck[i];  // L2-hot re-read (region resident in this XCD's L2)
    int pos = atomicAdd(&lcur[pv & (NBSZ - 1)], 1);
    epack[pos] = ((unsigned)pv) >> NBBITS;  // src only
  }
}

__global__ void dinv_rowptr_kernel(const int* __restrict__ rowptr, float* __restrict__ dinv,
                                   int N) {
  int i = blockIdx.x * blockDim.x + threadIdx.x;
  if (i < N) dinv[i] = rsqrtf((float)(rowptr[i + 1] - rowptr[i] + 1));
}

// ---------- GEMM: out[N,64] = x[N,K] @ W[K,64] (bias fused into agg) ----------

template <int K, typename OT>
__global__ __launch_bounds__(256, 4) void gemm_kernel(const float* __restrict__ x,
                                                      const float* __restrict__ W,
                                                      OT* __restrict__ out, int N) {
  __shared__ float Xs[64 * KT];  // [row][swizzled k-group]
  __shared__ float Ws[KT * 64];  // [kk][col]
  const int t = threadIdx.x;
  const int lane = t & 63;
  const int w = t >> 6;
  const int rg = lane >> 4;
  const int cg = lane & 15;
  const int row0 = blockIdx.x * 64;
  float4 acc[4];
#pragma unroll
  for (int r = 0; r < 4; ++r) acc[r] = make_float4(0.f, 0.f, 0.f, 0.f);

  for (int k0 = 0; k0 < K; k0 += KT) {
    if (k0) __syncthreads();
    const float* Wg = W + (size_t)k0 * HID;
#pragma unroll
    for (int c = 0; c < 4; ++c) {
      int idx = c * 256 + t;
      gld_lds16(Wg + idx * 4, &Ws[idx * 4]);
      int srow = idx >> 4;
      int sg = (idx & 15) ^ ((srow >> 2) & 3);
      int grow = min(row0 + srow, N - 1);
      gld_lds16(x + (size_t)grow * K + k0 + (sg << 2), &Xs[idx * 4]);
    }
    __syncthreads();
    const int rbase = w * 16 + rg * 4;
#pragma unroll 4
    for (int kb = 0; kb < KT / 4; ++kb) {
      float4 wq0 = *(const float4*)&Ws[(4 * kb + 0) * HID + cg * 4];
      float4 wq1 = *(const float4*)&Ws[(4 * kb + 1) * HID + cg * 4];
      float4 wq2 = *(const float4*)&Ws[(4 * kb + 2) * HID + cg * 4];
      float4 wq3 = *(const float4*)&Ws[(4 * kb + 3) * HID + cg * 4];
      const int sg = (kb ^ rg) << 2;
#pragma unroll
      for (int r = 0; r < 4; ++r) {
        float4 xv = *(const float4*)&Xs[(rbase + r) * KT + sg];
        acc[r].x = fmaf(xv.w, wq3.x, fmaf(xv.z, wq2.x, fmaf(xv.y, wq1.x, fmaf(xv.x, wq0.x, acc[r].x))));
        acc[r].y = fmaf(xv.w, wq3.y, fmaf(xv.z, wq2.y, fmaf(xv.y, wq1.y, fmaf(xv.x, wq0.y, acc[r].y))));
        acc[r].z = fmaf(xv.w, wq3.z, fmaf(xv.z, wq2.z, fmaf(xv.y, wq1.z, fmaf(xv.x, wq0.z, acc[r].z))));
        acc[r].w = fmaf(xv.w, wq3.w, fmaf(xv.z, wq2.w, fmaf(xv.y, wq1.w, fmaf(xv.x, wq0.w, acc[r].w))));
      }
    }
  }
#pragma unroll
  for (int r = 0; r < 4; ++r) {
    int row = row0 + w * 16 + rg * 4 + r;
    if (row < N) {
      OT* o = out + (size_t)row * HID + cg * 4;
      o[0] = (OT)acc[r].x; o[1] = (OT)acc[r].y; o[2] = (OT)acc[r].z; o[3] = (OT)acc[r].w;
    }
  }
}

// ---------- fused aggregation: 4 nodes/wave, 16 lanes/node, 4 feats/lane ----------
// epack holds src only; norm = dinv[dst]*dinv[src] computed inline (dinv table
// is 400KB, L2-hot, broadcast load per 16-lane quarter).

__device__ inline float bf_lo(unsigned int u) { return __uint_as_float(u << 16); }
__device__ inline float bf_hi(unsigned int u) { return __uint_as_float(u & 0xffff0000u); }

template <bool RELU_NORM>
__global__ void agg_kernel(const int* __restrict__ rowptr, const int* __restrict__ ep,
                           const float* __restrict__ dinv, const uint2* __restrict__ h64,
                           const float* __restrict__ bias, float* __restrict__ out, int N) {
  int grp = (blockIdx.x * blockDim.x + threadIdx.x) >> 6;
  int lane = threadIdx.x & 63;
  int q = lane >> 4;
  int sub = lane & 15;
  int node = grp * 4 + q;
  if (node >= N) return;
  int beg = rowptr[node];
  int end = rowptr[node + 1];
  float di = dinv[node];
  float dd = di * di;
  uint2 su = h64[(size_t)node * 16 + sub];
  float4 b4 = *(const float4*)&bias[sub * 4];
  float a0 = dd * bf_lo(su.x) + b4.x;
  float a1 = dd * bf_hi(su.x) + b4.y;
  float a2 = dd * bf_lo(su.y) + b4.z;
  float a3 = dd * bf_hi(su.y) + b4.w;
  int j = beg;
  for (; j + 8 <= end; j += 8) {
    int e[8];
    float dv[8];
    uint2 hv[8];
#pragma unroll
    for (int u = 0; u < 8; ++u) e[u] = ep[j + u];
#pragma unroll
    for (int u = 0; u < 8; ++u) dv[u] = dinv[e[u]];
#pragma unroll
    for (int u = 0; u < 8; ++u) hv[u] = h64[(size_t)e[u] * 16 + sub];
#pragma unroll
    for (int u = 0; u < 8; ++u) {
      float wn = di * dv[u];
      a0 = fmaf(wn, bf_lo(hv[u].x), a0);
      a1 = fmaf(wn, bf_hi(hv[u].x), a1);
      a2 = fmaf(wn, bf_lo(hv[u].y), a2);
      a3 = fmaf(wn, bf_hi(hv[u].y), a3);
    }
  }
  for (; j < end; ++j) {
    int e0 = ep[j];
    float wn = di * dinv[e0];
    uint2 hu = h64[(size_t)e0 * 16 + sub];
    a0 = fmaf(wn, bf_lo(hu.x), a0);
    a1 = fmaf(wn, bf_hi(hu.x), a1);
    a2 = fmaf(wn, bf_lo(hu.y), a2);
    a3 = fmaf(wn, bf_hi(hu.y), a3);
  }
  float4 v;
  if (RELU_NORM) {
    v.x = fmaxf(a0, 0.f); v.y = fmaxf(a1, 0.f);
    v.z = fmaxf(a2, 0.f); v.w = fmaxf(a3, 0.f);
    float ss = v.x * v.x + v.y * v.y + v.z * v.z + v.w * v.w;
#pragma unroll
    for (int off = 8; off; off >>= 1) ss += __shfl_xor(ss, off, 64);
    float inv = 1.f / fmaxf(sqrtf(ss), 1e-12f);
    v.x *= inv; v.y *= inv; v.z *= inv; v.w *= inv;
  } else {
    v = make_float4(a0, a1, a2, a3);
  }
  *(float4*)&out[(size_t)node * HID + sub * 4] = v;
}

// ---------- atomic fallback path (fp32; only if ws too small for CSR) ----------

__global__ void init_agg_kernel(const float* __restrict__ dinv, const float* __restrict__ h,
                                const float* __restrict__ bias, float* __restrict__ out, int N) {
  int t = blockIdx.x * blockDim.x + threadIdx.x;
  int i = t >> 6, f = t & 63;
  if (i >= N) return;
  float di = dinv[i];
  out[t] = di * di * h[t] + bias[f];
}

__global__ void edge_atomic_kernel(const int* __restrict__ src, const int* __restrict__ dst,
                                   const float* __restrict__ dinv, const float* __restrict__ h,
                                   float* __restrict__ out, int E) {
  int t = blockIdx.x * blockDim.x + threadIdx.x;
  int e = t >> 6;
  if (e >= E) return;
  int f = t & 63;
  int s = src[e], d = dst[e];
  atomicAdd(&out[(size_t)d * HID + f], dinv[s] * dinv[d] * h[(size_t)s * HID + f]);
}

__global__ void relu_norm_kernel(float* __restrict__ hbuf, int N) {
  int t = blockIdx.x * blockDim.x + threadIdx.x;
  int i = t >> 6;
  if (i >= N) return;
  float v = fmaxf(hbuf[t], 0.f);
  float ss = v * v;
#pragma unroll
  for (int off = 32; off; off >>= 1) ss += __shfl_xor(ss, off, 64);
  hbuf[t] = v / fmaxf(sqrtf(ss), 1e-12f);
}

// ---------- host ----------

extern "C" void kernel_launch(void* const* d_in, const int* in_sizes, int n_in,
                              void* d_out, int out_size, void* d_ws, size_t ws_size,
                              hipStream_t stream) {
  const float* x  = (const float*)d_in[0];
  const int*   ei = (const int*)d_in[1];
  const float* W1 = (const float*)d_in[2];
  const float* b1 = (const float*)d_in[3];
  const float* W2 = (const float*)d_in[4];
  const float* b2 = (const float*)d_in[5];
  const float* W3 = (const float*)d_in[6];
  const float* b3 = (const float*)d_in[7];
  float* out = (float*)d_out;

  const int IN = in_sizes[2] / HID;   // 256
  const int N  = in_sizes[0] / IN;    // 100000
  const int E  = in_sizes[1] / 2;     // 1600000
  const int* srcI = ei;
  const int* dstI = ei + E;
  const int B = (N + NBSZ - 1) >> NBBITS;  // buckets

  char* w = (char*)d_ws;
  size_t off = 0;
  auto alloc = [&](size_t bytes) { void* p = w + off; off = align256(off + bytes); return p; };
  float* A      = (float*)alloc((size_t)N * HID * 4);  // fp32 fallback / bf16 h / ebuck host
  float* dinv   = (float*)alloc((size_t)N * 4);
  int*   cnt    = (int*)alloc((size_t)N * 4);          // fallback only
  size_t base_need = off;
  int*   rowptr = (int*)alloc((size_t)(N + 1) * 4);
  int*   epack  = (int*)alloc((size_t)E * 4);          // src-only CSR payload
  int*   bbase  = (int*)alloc(1032 * 4);
  int*   gcur   = (int*)alloc(1024 * 4);
  int*   bcnt   = (int*)alloc(1024 * 4);
  size_t csr_need = off;

  if (base_need > ws_size) return;
  // CSR path constraints: ws fits; ebuck (E ints) fits inside A; pack fits 31 bits;
  // bucket count fits the pass-1 LDS tables and the 1024-wide scan.
  const bool use_csr = (csr_need <= ws_size) && (B <= P1_BMAX) &&
                       ((size_t)E <= (size_t)N * HID) && (N <= (1 << 20));
  __hip_bfloat16* Ab = (__hip_bfloat16*)A;
  uint2* Ab64 = (uint2*)A;
  int* ebuck = (int*)A;  // pass-1 output lives in A until gemm1 overwrites it

  const int blkE    = (E + 255) / 256;
  const int blkN    = (N + 255) / 256;
  const int blkRow  = (N + 63) / 64;
  const int blkWave = (N * 64 + 255) / 256;
  const int blkAgg  = ((size_t)((N + 3) / 4) * 64 + 255) / 256;  // 4 nodes/wave
  const int blkEF   = ((size_t)E * 64 + 255) / 256;
  const int blkBkt  = (E + P1_CH - 1) / P1_CH;

  if (use_csr) {
    hipMemsetAsync(bcnt, 0, 1024 * 4, stream);
    bucket_count_kernel<<<256, 256, 0, stream>>>(dstI, bcnt, E, B);
    bucket_scan_kernel<<<1, 1024, 0, stream>>>(bcnt, bbase, gcur, B);
    bucketize_kernel<<<blkBkt, 256, 0, stream>>>(srcI, dstI, gcur, ebuck, E);
    bucket_sort_kernel<<<B, 1024, 0, stream>>>(ebuck, bbase, rowptr, epack, N, B, E);
    dinv_rowptr_kernel<<<blkN, 256, 0, stream>>>(rowptr, dinv, N);

    gemm_kernel<256><<<blkRow, 256, 0, stream>>>(x, W1, Ab, N);
    agg_kernel<true><<<blkAgg, 256, 0, stream>>>(rowptr, epack, dinv, Ab64, b1, out, N);
    gemm_kernel<64><<<blkRow, 256, 0, stream>>>(out, W2, Ab, N);
    agg_kernel<true><<<blkAgg, 256, 0, stream>>>(rowptr, epack, dinv, Ab64, b2, out, N);
    gemm_kernel<64><<<blkRow, 256, 0, stream>>>(out, W3, Ab, N);
    agg_kernel<false><<<blkAgg, 256, 0, stream>>>(rowptr, epack, dinv, Ab64, b3, out, N);
  } else {
    hipMemsetAsync(cnt, 0, (size_t)N * 4, stream);
    count_dst_kernel<<<blkE, 256, 0, stream>>>(dstI, cnt, E);
    dinv_kernel<<<blkN, 256, 0, stream>>>(cnt, dinv, N);

    gemm_kernel<256><<<blkRow, 256, 0, stream>>>(x, W1, A, N);
    init_agg_kernel<<<blkWave, 256, 0, stream>>>(dinv, A, b1, out, N);
    edge_atomic_kernel<<<blkEF, 256, 0, stream>>>(srcI, dstI, dinv, A, out, E);
    relu_norm_kernel<<<blkWave, 256, 0, stream>>>(out, N);

    gemm_kernel<64><<<blkRow, 256, 0, stream>>>(out, W2, A, N);
    init_agg_kernel<<<blkWave, 256, 0, stream>>>(dinv, A, b2, out, N);
    edge_atomic_kernel<<<blkEF, 256, 0, stream>>>(srcI, dstI, dinv, A, out, E);
    relu_norm_kernel<<<blkWave, 256, 0, stream>>>(out, N);

    gemm_kernel<64><<<blkRow, 256, 0, stream>>>(out, W3, A, N);
    init_agg_kernel<<<blkWave, 256, 0, stream>>>(dinv, A, b3, out, N);
    edge_atomic_kernel<<<blkEF, 256, 0, stream>>>(srcI, dstI, dinv, A, out, E);
  }
}

// Round 2
// 387.197 us; speedup vs baseline: 1.2572x; 1.0755x over previous
//
#include <hip/hip_runtime.h>
#include <hip/hip_bf16.h>
#include <math.h>

#define HID 64
#define KT 64

#define NBBITS 10
#define NBSZ 1024       // nodes per bucket
#define P1_BMAX 128     // max buckets supported by bucketize LDS
#define P1_CH 4096      // edges per bucketize block
#define P1_CAP 96       // LDS list capacity per bucket (mean ~42 at E/N=16)

typedef __attribute__((ext_vector_type(8))) short s16x8;   // 8 bf16 (4 VGPR)
typedef __attribute__((ext_vector_type(4))) float f32x4;   // mfma accumulator

static inline size_t align256(size_t x) { return (x + 255) & ~(size_t)255; }

__device__ inline void gld_lds16(const float* g, float* lds) {
  __builtin_amdgcn_global_load_lds((const __attribute__((address_space(1))) void*)g,
                                   (__attribute__((address_space(3))) void*)lds, 16, 0, 0);
}

__device__ inline unsigned short f2bf(float f) {  // RNE f32 -> bf16 bits
  unsigned u = __float_as_uint(f);
  return (unsigned short)((u + 0x7FFFu + ((u >> 16) & 1u)) >> 16);
}
__device__ inline float bf2f(unsigned short h) { return __uint_as_float(((unsigned)h) << 16); }
__device__ inline float bf_lo(unsigned int u) { return __uint_as_float(u << 16); }
__device__ inline float bf_hi(unsigned int u) { return __uint_as_float(u & 0xffff0000u); }

// ---------- fallback-path degree count ----------

__global__ void count_dst_kernel(const int* __restrict__ dst, int* __restrict__ cnt, int E) {
  int e = blockIdx.x * blockDim.x + threadIdx.x;
  if (e < E) atomicAdd(&cnt[dst[e]], 1);
}

__global__ void dinv_kernel(const int* __restrict__ cnt, float* __restrict__ dinv, int N) {
  int i = blockIdx.x * blockDim.x + threadIdx.x;
  if (i < N) dinv[i] = rsqrtf((float)(cnt[i] + 1));  // +1 self-loop
}

// ---------- CSR path: 2-pass bucket sort ----------

__global__ void bucket_count_kernel(const int* __restrict__ dst, int* __restrict__ bcnt,
                                    int E, int B) {
  __shared__ int sh[1024];
  for (int i = threadIdx.x; i < B; i += blockDim.x) sh[i] = 0;
  __syncthreads();
  for (int e = blockIdx.x * blockDim.x + threadIdx.x; e < E; e += gridDim.x * blockDim.x)
    atomicAdd(&sh[dst[e] >> NBBITS], 1);
  __syncthreads();
  for (int i = threadIdx.x; i < B; i += blockDim.x) {
    int v = sh[i];
    if (v) atomicAdd(&bcnt[i], v);
  }
}

__global__ __launch_bounds__(1024) void bucket_scan_kernel(const int* __restrict__ bcnt,
                                                           int* __restrict__ bbase,
                                                           int* __restrict__ gcur, int B) {
  __shared__ int sh[1024];
  int t = threadIdx.x;
  int v = (t < B) ? bcnt[t] : 0;
  sh[t] = v;
  __syncthreads();
  for (int off = 1; off < 1024; off <<= 1) {
    int u = (t >= off) ? sh[t - off] : 0;
    __syncthreads();
    sh[t] += u;
    __syncthreads();
  }
  if (t < B) {
    int ex = sh[t] - v;
    bbase[t] = ex;
    gcur[t] = ex;
  }
  if (t == 1023) bbase[B] = sh[1023];
}

// pass 1: partition edges into bucket regions with wave-coalesced chunk flushes.
__global__ __launch_bounds__(256) void bucketize_kernel(const int* __restrict__ src,
                                                        const int* __restrict__ dst,
                                                        int* __restrict__ gcur,
                                                        int* __restrict__ ebuck, int E) {
  __shared__ int cnt[P1_BMAX];
  __shared__ int lists[P1_BMAX * P1_CAP];
  int t = threadIdx.x;
  for (int i = t; i < P1_BMAX; i += 256) cnt[i] = 0;
  __syncthreads();
  int base_e = blockIdx.x * P1_CH;
#pragma unroll
  for (int u = 0; u < P1_CH / 256; ++u) {
    int e = base_e + u * 256 + t;
    if (e < E) {
      int s = src[e], d = dst[e];
      int bk = d >> NBBITS;
      int packed = (s << NBBITS) | (d & (NBSZ - 1));
      int p = atomicAdd(&cnt[bk], 1);
      if (p < P1_CAP) {
        lists[bk * P1_CAP + p] = packed;
      } else {  // rare statistical overflow: direct scattered write, still correct
        int gp = atomicAdd(&gcur[bk], 1);
        ebuck[gp] = packed;
      }
    }
  }
  __syncthreads();
  int w = t >> 6, lane = t & 63;
  int bk = w * 32 + (lane & 31);
  int c = min(cnt[bk], P1_CAP);
  int mybase = 0;
  if (lane < 32 && c > 0) mybase = atomicAdd(&gcur[bk], c);
#pragma unroll 1
  for (int i = 0; i < 32; ++i) {
    int cb = __shfl(c, i);
    if (cb == 0) continue;
    int gb = __shfl(mybase, i);
    int bb = w * 32 + i;
    if (lane < cb) ebuck[gb + lane] = lists[bb * P1_CAP + lane];
    if (cb > 64 && lane < cb - 64) ebuck[gb + 64 + lane] = lists[bb * P1_CAP + 64 + lane];
  }
}

// pass 2: one block owns one bucket exclusively; writes rowptr, dinv, and the
// src-sorted epack (scatter confined to this block's contiguous region).
__global__ __launch_bounds__(1024) void bucket_sort_kernel(const int* __restrict__ ebuck,
                                                           const int* __restrict__ bbase,
                                                           int* __restrict__ rowptr,
                                                           int* __restrict__ epack,
                                                           float* __restrict__ dinv,
                                                           int N, int B, int E) {
  __shared__ int lcnt[NBSZ];
  __shared__ int lcur[NBSZ];
  int b = blockIdx.x;
  int t = threadIdx.x;
  int n0 = b << NBBITS;
  lcnt[t] = 0;
  __syncthreads();
  int e0 = bbase[b], e1 = bbase[b + 1];
  for (int i = e0 + t; i < e1; i += 1024) atomicAdd(&lcnt[ebuck[i] & (NBSZ - 1)], 1);
  __syncthreads();
  int v = lcnt[t];
  for (int off = 1; off < 1024; off <<= 1) {
    int u = (t >= off) ? lcnt[t - off] : 0;
    __syncthreads();
    lcnt[t] += u;
    __syncthreads();
  }
  int ex = lcnt[t] - v;
  int node = n0 + t;
  if (node < N) {
    rowptr[node] = e0 + ex;
    dinv[node] = rsqrtf((float)(v + 1));  // degree+self-loop
  }
  if (b == B - 1 && t == 0) rowptr[N] = E;
  lcur[t] = e0 + ex;
  __syncthreads();
  for (int i = e0 + t; i < e1; i += 1024) {
    int pv = ebuck[i];
    int pos = atomicAdd(&lcur[pv & (NBSZ - 1)], 1);
    epack[pos] = ((unsigned)pv) >> NBBITS;  // src only
  }
}

// ---------- W prep: fp32 W -> hi/lo bf16 in MFMA fragment order ----------
// Fragment order (A-operand of mfma(W,x)): elem (s,ct,lane,j) = W[k][col],
// k = s*32 + (lane>>4)*8 + j, col = ct*16 + (lane&15); linear idx =
// ((s*4+ct)*64 + lane)*8 + j.

__global__ void wprep_kernel(const float* __restrict__ W1, const float* __restrict__ W2,
                             const float* __restrict__ W3, unsigned short* __restrict__ W1h,
                             unsigned short* __restrict__ W1l, unsigned short* __restrict__ W2h,
                             unsigned short* __restrict__ W2l, unsigned short* __restrict__ W3h,
                             unsigned short* __restrict__ W3l) {
  int b = blockIdx.x, t = threadIdx.x;
  const float* W;
  unsigned short *Dh, *Dl;
  int idx;
  if (b < 64)      { W = W1; Dh = W1h; Dl = W1l; idx = b * 256 + t; }
  else if (b < 80) { W = W2; Dh = W2h; Dl = W2l; idx = (b - 64) * 256 + t; }
  else             { W = W3; Dh = W3h; Dl = W3l; idx = (b - 80) * 256 + t; }
  int j = idx & 7, lane = (idx >> 3) & 63, ct = (idx >> 9) & 3, s = idx >> 11;
  int k = s * 32 + ((lane >> 4) << 3) + j;
  int col = ct * 16 + (lane & 15);
  float f = W[k * HID + col];
  unsigned short h = f2bf(f);
  Dh[idx] = h;
  Dl[idx] = f2bf(f - bf2f(h));
}

// ---------- split-bf16 MFMA GEMM: out_bf16[N,64] = dinv[row] * (x[N,K] @ W[K,64]) ----------
// mfma(A=W^T frag, B=x^T frag): D[m=Wcol][n=xrow]; lane's acc[ct][r] =
// out[row0+w*16+(lane&15)][ct*16+(lane>>4)*4+r] -> 8B coalesced bf16 stores.
// x staged fp32 via global_load_lds, 16B granules XOR-swizzled by (row&7) on
// the GLOBAL side so fragment ds_read_b128 spreads uniformly over 32 banks.

template <int K>
__global__ __launch_bounds__(256, 4) void gemm_mfma_kernel(
    const float* __restrict__ x, const unsigned short* __restrict__ Wh,
    const unsigned short* __restrict__ Wl, const float* __restrict__ dinv,
    unsigned short* __restrict__ out, int N) {
  constexpr int NS = K / 32;
  __shared__ float xs[2][64 * 32];  // 8KB per k-step buffer
  const int t = threadIdx.x, lane = t & 63, w = t >> 6;
  const int g = lane >> 4, r15 = lane & 15;
  const int row0 = blockIdx.x * 64;
  const int arow = w * 16 + r15;  // this lane's x-row within the 64-row tile
  f32x4 acc[4];
#pragma unroll
  for (int ct = 0; ct < 4; ++ct) acc[ct] = (f32x4){0.f, 0.f, 0.f, 0.f};

  auto stage = [&](int buf, int s) {
#pragma unroll
    for (int c = 0; c < 2; ++c) {
      int idx = c * 256 + t;          // granule slot (64 rows x 8 granules)
      int row = idx >> 3, gp = idx & 7;
      int gs = gp ^ (row & 7);        // pre-swizzled global granule
      int grow = min(row0 + row, N - 1);
      gld_lds16(x + (size_t)grow * K + s * 32 + gs * 4, &xs[buf][idx * 4]);
    }
  };
  stage(0, 0);
  for (int s = 0; s < NS; ++s) {
    __syncthreads();                      // drains vmcnt: buf[s&1] ready
    if (s + 1 < NS) stage((s + 1) & 1, s + 1);
    const float* xb = &xs[s & 1][arow * 32];
    float4 xv0 = *(const float4*)&xb[((2 * g) ^ (arow & 7)) * 4];
    float4 xv1 = *(const float4*)&xb[((2 * g + 1) ^ (arow & 7)) * 4];
    float xf[8] = {xv0.x, xv0.y, xv0.z, xv0.w, xv1.x, xv1.y, xv1.z, xv1.w};
    s16x8 xh, xl;
#pragma unroll
    for (int j = 0; j < 8; ++j) {
      unsigned short hb = f2bf(xf[j]);
      xh[j] = (short)hb;
      xl[j] = (short)f2bf(xf[j] - bf2f(hb));
    }
#pragma unroll
    for (int ct = 0; ct < 4; ++ct) {
      size_t o = (((size_t)(s * 4 + ct)) * 64 + lane) * 8;
      s16x8 wh = *(const s16x8*)&Wh[o];
      s16x8 wl = *(const s16x8*)&Wl[o];
      acc[ct] = __builtin_amdgcn_mfma_f32_16x16x32_bf16(wh, xh, acc[ct], 0, 0, 0);
      acc[ct] = __builtin_amdgcn_mfma_f32_16x16x32_bf16(wl, xh, acc[ct], 0, 0, 0);
      acc[ct] = __builtin_amdgcn_mfma_f32_16x16x32_bf16(wh, xl, acc[ct], 0, 0, 0);
    }
  }
  int row = row0 + arow;
  if (row < N) {
    float di = dinv[row];  // prescale: agg then needs no per-edge dinv gather
    unsigned short* orow = out + (size_t)row * HID;
#pragma unroll
    for (int ct = 0; ct < 4; ++ct) {
      unsigned p0 = (unsigned)f2bf(di * acc[ct][0]) | ((unsigned)f2bf(di * acc[ct][1]) << 16);
      unsigned p1 = (unsigned)f2bf(di * acc[ct][2]) | ((unsigned)f2bf(di * acc[ct][3]) << 16);
      *(uint2*)&orow[ct * 16 + g * 4] = make_uint2(p0, p1);
    }
  }
}

// ---------- fused aggregation: 4 nodes/wave, 16 lanes/node, 4 feats/lane ----------
// h64 holds hs = dinv[row]*h (prescaled by gemm epilogue), so:
// out[d] = dinv[d]*(hs[d] + sum_e hs[src_e]) + b  (+relu+L2norm)
// Per-edge work is one uint2 gather + 4 adds; no dinv gather, no multiply.

template <bool RELU_NORM>
__global__ void agg_kernel(const int* __restrict__ rowptr, const int* __restrict__ ep,
                           const float* __restrict__ dinv, const uint2* __restrict__ h64,
                           const float* __restrict__ bias, float* __restrict__ out, int N) {
  int grp = (blockIdx.x * blockDim.x + threadIdx.x) >> 6;
  int lane = threadIdx.x & 63;
  int q = lane >> 4;
  int sub = lane & 15;
  int node = grp * 4 + q;
  if (node >= N) return;
  int beg = rowptr[node];
  int end = rowptr[node + 1];
  uint2 su = h64[(size_t)node * 16 + sub];  // self term (dinv^2*h after final *di)
  float a0 = bf_lo(su.x), a1 = bf_hi(su.x), a2 = bf_lo(su.y), a3 = bf_hi(su.y);
  int j = beg;
  for (; j + 8 <= end; j += 8) {
    int e[8];
    uint2 hv[8];
#pragma unroll
    for (int u = 0; u < 8; ++u) e[u] = ep[j + u];
#pragma unroll
    for (int u = 0; u < 8; ++u) hv[u] = h64[(size_t)e[u] * 16 + sub];
#pragma unroll
    for (int u = 0; u < 8; ++u) {
      a0 += bf_lo(hv[u].x); a1 += bf_hi(hv[u].x);
      a2 += bf_lo(hv[u].y); a3 += bf_hi(hv[u].y);
    }
  }
  for (; j < end; ++j) {
    uint2 hu = h64[(size_t)ep[j] * 16 + sub];
    a0 += bf_lo(hu.x); a1 += bf_hi(hu.x); a2 += bf_lo(hu.y); a3 += bf_hi(hu.y);
  }
  float di = dinv[node];
  float4 b4 = *(const float4*)&bias[sub * 4];
  float4 v;
  v.x = fmaf(di, a0, b4.x); v.y = fmaf(di, a1, b4.y);
  v.z = fmaf(di, a2, b4.z); v.w = fmaf(di, a3, b4.w);
  if (RELU_NORM) {
    v.x = fmaxf(v.x, 0.f); v.y = fmaxf(v.y, 0.f);
    v.z = fmaxf(v.z, 0.f); v.w = fmaxf(v.w, 0.f);
    float ss = v.x * v.x + v.y * v.y + v.z * v.z + v.w * v.w;
#pragma unroll
    for (int off = 8; off; off >>= 1) ss += __shfl_xor(ss, off, 64);  // 16-lane quarter
    float inv = 1.f / fmaxf(sqrtf(ss), 1e-12f);
    v.x *= inv; v.y *= inv; v.z *= inv; v.w *= inv;
  }
  *(float4*)&out[(size_t)node * HID + sub * 4] = v;
}

// ---------- vector GEMM (fallback path only, fp32 out, no prescale) ----------

template <int K, typename OT>
__global__ __launch_bounds__(256, 4) void gemm_kernel(const float* __restrict__ x,
                                                      const float* __restrict__ W,
                                                      OT* __restrict__ out, int N) {
  __shared__ float Xs[64 * KT];
  __shared__ float Ws[KT * 64];
  const int t = threadIdx.x;
  const int lane = t & 63;
  const int w = t >> 6;
  const int rg = lane >> 4;
  const int cg = lane & 15;
  const int row0 = blockIdx.x * 64;
  float4 acc[4];
#pragma unroll
  for (int r = 0; r < 4; ++r) acc[r] = make_float4(0.f, 0.f, 0.f, 0.f);

  for (int k0 = 0; k0 < K; k0 += KT) {
    if (k0) __syncthreads();
    const float* Wg = W + (size_t)k0 * HID;
#pragma unroll
    for (int c = 0; c < 4; ++c) {
      int idx = c * 256 + t;
      gld_lds16(Wg + idx * 4, &Ws[idx * 4]);
      int srow = idx >> 4;
      int sg = (idx & 15) ^ ((srow >> 2) & 3);
      int grow = min(row0 + srow, N - 1);
      gld_lds16(x + (size_t)grow * K + k0 + (sg << 2), &Xs[idx * 4]);
    }
    __syncthreads();
    const int rbase = w * 16 + rg * 4;
#pragma unroll 4
    for (int kb = 0; kb < KT / 4; ++kb) {
      float4 wq0 = *(const float4*)&Ws[(4 * kb + 0) * HID + cg * 4];
      float4 wq1 = *(const float4*)&Ws[(4 * kb + 1) * HID + cg * 4];
      float4 wq2 = *(const float4*)&Ws[(4 * kb + 2) * HID + cg * 4];
      float4 wq3 = *(const float4*)&Ws[(4 * kb + 3) * HID + cg * 4];
      const int sg = (kb ^ rg) << 2;
#pragma unroll
      for (int r = 0; r < 4; ++r) {
        float4 xv = *(const float4*)&Xs[(rbase + r) * KT + sg];
        acc[r].x = fmaf(xv.w, wq3.x, fmaf(xv.z, wq2.x, fmaf(xv.y, wq1.x, fmaf(xv.x, wq0.x, acc[r].x))));
        acc[r].y = fmaf(xv.w, wq3.y, fmaf(xv.z, wq2.y, fmaf(xv.y, wq1.y, fmaf(xv.x, wq0.y, acc[r].y))));
        acc[r].z = fmaf(xv.w, wq3.z, fmaf(xv.z, wq2.z, fmaf(xv.y, wq1.z, fmaf(xv.x, wq0.z, acc[r].z))));
        acc[r].w = fmaf(xv.w, wq3.w, fmaf(xv.z, wq2.w, fmaf(xv.y, wq1.w, fmaf(xv.x, wq0.w, acc[r].w))));
      }
    }
  }
#pragma unroll
  for (int r = 0; r < 4; ++r) {
    int row = row0 + w * 16 + rg * 4 + r;
    if (row < N) {
      OT* o = out + (size_t)row * HID + cg * 4;
      o[0] = (OT)acc[r].x; o[1] = (OT)acc[r].y; o[2] = (OT)acc[r].z; o[3] = (OT)acc[r].w;
    }
  }
}

// ---------- atomic fallback path ----------

__global__ void init_agg_kernel(const float* __restrict__ dinv, const float* __restrict__ h,
                                const float* __restrict__ bias, float* __restrict__ out, int N) {
  int t = blockIdx.x * blockDim.x + threadIdx.x;
  int i = t >> 6, f = t & 63;
  if (i >= N) return;
  float di = dinv[i];
  out[t] = di * di * h[t] + bias[f];
}

__global__ void edge_atomic_kernel(const int* __restrict__ src, const int* __restrict__ dst,
                                   const float* __restrict__ dinv, const float* __restrict__ h,
                                   float* __restrict__ out, int E) {
  int t = blockIdx.x * blockDim.x + threadIdx.x;
  int e = t >> 6;
  if (e >= E) return;
  int f = t & 63;
  int s = src[e], d = dst[e];
  atomicAdd(&out[(size_t)d * HID + f], dinv[s] * dinv[d] * h[(size_t)s * HID + f]);
}

__global__ void relu_norm_kernel(float* __restrict__ hbuf, int N) {
  int t = blockIdx.x * blockDim.x + threadIdx.x;
  int i = t >> 6;
  if (i >= N) return;
  float v = fmaxf(hbuf[t], 0.f);
  float ss = v * v;
#pragma unroll
  for (int off = 32; off; off >>= 1) ss += __shfl_xor(ss, off, 64);
  hbuf[t] = v / fmaxf(sqrtf(ss), 1e-12f);
}

// ---------- host ----------

extern "C" void kernel_launch(void* const* d_in, const int* in_sizes, int n_in,
                              void* d_out, int out_size, void* d_ws, size_t ws_size,
                              hipStream_t stream) {
  const float* x  = (const float*)d_in[0];
  const int*   ei = (const int*)d_in[1];
  const float* W1 = (const float*)d_in[2];
  const float* b1 = (const float*)d_in[3];
  const float* W2 = (const float*)d_in[4];
  const float* b2 = (const float*)d_in[5];
  const float* W3 = (const float*)d_in[6];
  const float* b3 = (const float*)d_in[7];
  float* out = (float*)d_out;

  const int IN = in_sizes[2] / HID;   // 256
  const int N  = in_sizes[0] / IN;    // 100000
  const int E  = in_sizes[1] / 2;     // 1600000
  const int* srcI = ei;
  const int* dstI = ei + E;
  const int B = (N + NBSZ - 1) >> NBBITS;

  char* w = (char*)d_ws;
  size_t off = 0;
  auto alloc = [&](size_t bytes) { void* p = w + off; off = align256(off + bytes); return p; };
  float* A      = (float*)alloc((size_t)N * HID * 4);  // fp32 fallback / bf16 hs / ebuck host
  float* dinv   = (float*)alloc((size_t)N * 4);
  int*   cnt    = (int*)alloc((size_t)N * 4);          // fallback only
  size_t base_need = off;
  int*   rowptr = (int*)alloc((size_t)(N + 1) * 4);
  int*   epack  = (int*)alloc((size_t)E * 4);          // src-only CSR payload
  int*   bbase  = (int*)alloc(1032 * 4);
  int*   gcur   = (int*)alloc(1024 * 4);
  int*   bcnt   = (int*)alloc(1024 * 4);
  unsigned short* W1h = (unsigned short*)alloc(16384 * 2);
  unsigned short* W1l = (unsigned short*)alloc(16384 * 2);
  unsigned short* W2h = (unsigned short*)alloc(4096 * 2);
  unsigned short* W2l = (unsigned short*)alloc(4096 * 2);
  unsigned short* W3h = (unsigned short*)alloc(4096 * 2);
  unsigned short* W3l = (unsigned short*)alloc(4096 * 2);
  size_t csr_need = off;

  if (base_need > ws_size) return;
  const bool use_csr = (csr_need <= ws_size) && (B <= P1_BMAX) &&
                       ((size_t)E <= (size_t)N * HID) && (N <= (1 << 20));
  uint2* Ab64 = (uint2*)A;
  unsigned short* Abs = (unsigned short*)A;
  int* ebuck = (int*)A;  // pass-1 output lives in A until gemm1 overwrites it

  const int blkE    = (E + 255) / 256;
  const int blkN    = (N + 255) / 256;
  const int blkRow  = (N + 63) / 64;
  const int blkWave = (N * 64 + 255) / 256;
  const int blkAgg  = ((size_t)((N + 3) / 4) * 64 + 255) / 256;
  const int blkEF   = ((size_t)E * 64 + 255) / 256;
  const int blkBkt  = (E + P1_CH - 1) / P1_CH;

  if (use_csr) {
    hipMemsetAsync(bcnt, 0, 1024 * 4, stream);
    wprep_kernel<<<96, 256, 0, stream>>>(W1, W2, W3, W1h, W1l, W2h, W2l, W3h, W3l);
    bucket_count_kernel<<<256, 256, 0, stream>>>(dstI, bcnt, E, B);
    bucket_scan_kernel<<<1, 1024, 0, stream>>>(bcnt, bbase, gcur, B);
    bucketize_kernel<<<blkBkt, 256, 0, stream>>>(srcI, dstI, gcur, ebuck, E);
    bucket_sort_kernel<<<B, 1024, 0, stream>>>(ebuck, bbase, rowptr, epack, dinv, N, B, E);

    gemm_mfma_kernel<256><<<blkRow, 256, 0, stream>>>(x, W1h, W1l, dinv, Abs, N);
    agg_kernel<true><<<blkAgg, 256, 0, stream>>>(rowptr, epack, dinv, Ab64, b1, out, N);
    gemm_mfma_kernel<64><<<blkRow, 256, 0, stream>>>(out, W2h, W2l, dinv, Abs, N);
    agg_kernel<true><<<blkAgg, 256, 0, stream>>>(rowptr, epack, dinv, Ab64, b2, out, N);
    gemm_mfma_kernel<64><<<blkRow, 256, 0, stream>>>(out, W3h, W3l, dinv, Abs, N);
    agg_kernel<false><<<blkAgg, 256, 0, stream>>>(rowptr, epack, dinv, Ab64, b3, out, N);
  } else {
    hipMemsetAsync(cnt, 0, (size_t)N * 4, stream);
    count_dst_kernel<<<blkE, 256, 0, stream>>>(dstI, cnt, E);
    dinv_kernel<<<blkN, 256, 0, stream>>>(cnt, dinv, N);

    gemm_kernel<256><<<blkRow, 256, 0, stream>>>(x, W1, A, N);
    init_agg_kernel<<<blkWave, 256, 0, stream>>>(dinv, A, b1, out, N);
    edge_atomic_kernel<<<blkEF, 256, 0, stream>>>(srcI, dstI, dinv, A, out, E);
    relu_norm_kernel<<<blkWave, 256, 0, stream>>>(out, N);

    gemm_kernel<64><<<blkRow, 256, 0, stream>>>(out, W2, A, N);
    init_agg_kernel<<<blkWave, 256, 0, stream>>>(dinv, A, b2, out, N);
    edge_atomic_kernel<<<blkEF, 256, 0, stream>>>(srcI, dstI, dinv, A, out, E);
    relu_norm_kernel<<<blkWave, 256, 0, stream>>>(out, N);

    gemm_kernel<64><<<blkRow, 256, 0, stream>>>(out, W3, A, N);
    init_agg_kernel<<<blkWave, 256, 0, stream>>>(dinv, A, b3, out, N);
    edge_atomic_kernel<<<blkEF, 256, 0, stream>>>(srcI, dstI, dinv, A, out, E);
  }
}

// Round 3
// 381.580 us; speedup vs baseline: 1.2757x; 1.0147x over previous
//
#include <hip/hip_runtime.h>
#include <hip/hip_bf16.h>
#include <math.h>

#define HID 64
#define KT 64

#define NBBITS 10
#define NBSZ 1024       // nodes per bucket
#define P1_BMAX 128     // max buckets supported by bucketize LDS
#define P1_CH 4096      // edges per bucketize block
#define P1_CAP 96       // LDS list capacity per bucket (mean ~42 at E/N=16)

typedef __attribute__((ext_vector_type(8))) short s16x8;   // 8 bf16 (4 VGPR)
typedef __attribute__((ext_vector_type(4))) float f32x4;   // mfma accumulator

static inline size_t align256(size_t x) { return (x + 255) & ~(size_t)255; }

__device__ inline void gld_lds16(const float* g, float* lds) {
  __builtin_amdgcn_global_load_lds((const __attribute__((address_space(1))) void*)g,
                                   (__attribute__((address_space(3))) void*)lds, 16, 0, 0);
}

__device__ inline unsigned short f2bf(float f) {  // RNE f32 -> bf16 bits
  unsigned u = __float_as_uint(f);
  return (unsigned short)((u + 0x7FFFu + ((u >> 16) & 1u)) >> 16);
}
__device__ inline float bf2f(unsigned short h) { return __uint_as_float(((unsigned)h) << 16); }
__device__ inline float bf_lo(unsigned int u) { return __uint_as_float(u << 16); }
__device__ inline float bf_hi(unsigned int u) { return __uint_as_float(u & 0xffff0000u); }

// ---------- fallback-path degree count ----------

__global__ void count_dst_kernel(const int* __restrict__ dst, int* __restrict__ cnt, int E) {
  int e = blockIdx.x * blockDim.x + threadIdx.x;
  if (e < E) atomicAdd(&cnt[dst[e]], 1);
}

__global__ void dinv_kernel(const int* __restrict__ cnt, float* __restrict__ dinv, int N) {
  int i = blockIdx.x * blockDim.x + threadIdx.x;
  if (i < N) dinv[i] = rsqrtf((float)(cnt[i] + 1));  // +1 self-loop
}

// ---------- CSR path: 2-pass bucket sort ----------

__global__ void bucket_count_kernel(const int* __restrict__ dst, int* __restrict__ bcnt,
                                    int E, int B) {
  __shared__ int sh[1024];
  for (int i = threadIdx.x; i < B; i += blockDim.x) sh[i] = 0;
  __syncthreads();
  for (int e = blockIdx.x * blockDim.x + threadIdx.x; e < E; e += gridDim.x * blockDim.x)
    atomicAdd(&sh[dst[e] >> NBBITS], 1);
  __syncthreads();
  for (int i = threadIdx.x; i < B; i += blockDim.x) {
    int v = sh[i];
    if (v) atomicAdd(&bcnt[i], v);
  }
}

__global__ __launch_bounds__(1024) void bucket_scan_kernel(const int* __restrict__ bcnt,
                                                           int* __restrict__ bbase,
                                                           int* __restrict__ gcur, int B) {
  __shared__ int sh[1024];
  int t = threadIdx.x;
  int v = (t < B) ? bcnt[t] : 0;
  sh[t] = v;
  __syncthreads();
  for (int off = 1; off < 1024; off <<= 1) {
    int u = (t >= off) ? sh[t - off] : 0;
    __syncthreads();
    sh[t] += u;
    __syncthreads();
  }
  if (t < B) {
    int ex = sh[t] - v;
    bbase[t] = ex;
    gcur[t] = ex;
  }
  if (t == 1023) bbase[B] = sh[1023];
}

// pass 1: partition edges into bucket regions with wave-coalesced chunk flushes.
__global__ __launch_bounds__(256) void bucketize_kernel(const int* __restrict__ src,
                                                        const int* __restrict__ dst,
                                                        int* __restrict__ gcur,
                                                        int* __restrict__ ebuck, int E) {
  __shared__ int cnt[P1_BMAX];
  __shared__ int lists[P1_BMAX * P1_CAP];
  int t = threadIdx.x;
  for (int i = t; i < P1_BMAX; i += 256) cnt[i] = 0;
  __syncthreads();
  int base_e = blockIdx.x * P1_CH;
#pragma unroll
  for (int u = 0; u < P1_CH / 256; ++u) {
    int e = base_e + u * 256 + t;
    if (e < E) {
      int s = src[e], d = dst[e];
      int bk = d >> NBBITS;
      int packed = (s << NBBITS) | (d & (NBSZ - 1));
      int p = atomicAdd(&cnt[bk], 1);
      if (p < P1_CAP) {
        lists[bk * P1_CAP + p] = packed;
      } else {  // rare statistical overflow: direct scattered write, still correct
        int gp = atomicAdd(&gcur[bk], 1);
        ebuck[gp] = packed;
      }
    }
  }
  __syncthreads();
  int w = t >> 6, lane = t & 63;
  int bk = w * 32 + (lane & 31);
  int c = min(cnt[bk], P1_CAP);
  int mybase = 0;
  if (lane < 32 && c > 0) mybase = atomicAdd(&gcur[bk], c);
#pragma unroll 1
  for (int i = 0; i < 32; ++i) {
    int cb = __shfl(c, i);
    if (cb == 0) continue;
    int gb = __shfl(mybase, i);
    int bb = w * 32 + i;
    if (lane < cb) ebuck[gb + lane] = lists[bb * P1_CAP + lane];
    if (cb > 64 && lane < cb - 64) ebuck[gb + 64 + lane] = lists[bb * P1_CAP + 64 + lane];
  }
}

// pass 2: one block owns one bucket exclusively; writes rowptr, dinv, and the
// src-sorted epack (scatter confined to this block's contiguous region).
__global__ __launch_bounds__(1024) void bucket_sort_kernel(const int* __restrict__ ebuck,
                                                           const int* __restrict__ bbase,
                                                           int* __restrict__ rowptr,
                                                           int* __restrict__ epack,
                                                           float* __restrict__ dinv,
                                                           int N, int B, int E) {
  __shared__ int lcnt[NBSZ];
  __shared__ int lcur[NBSZ];
  int b = blockIdx.x;
  int t = threadIdx.x;
  int n0 = b << NBBITS;
  lcnt[t] = 0;
  __syncthreads();
  int e0 = bbase[b], e1 = bbase[b + 1];
  for (int i = e0 + t; i < e1; i += 1024) atomicAdd(&lcnt[ebuck[i] & (NBSZ - 1)], 1);
  __syncthreads();
  int v = lcnt[t];
  for (int off = 1; off < 1024; off <<= 1) {
    int u = (t >= off) ? lcnt[t - off] : 0;
    __syncthreads();
    lcnt[t] += u;
    __syncthreads();
  }
  int ex = lcnt[t] - v;
  int node = n0 + t;
  if (node < N) {
    rowptr[node] = e0 + ex;
    dinv[node] = rsqrtf((float)(v + 1));  // degree+self-loop
  }
  if (b == B - 1 && t == 0) rowptr[N] = E;
  lcur[t] = e0 + ex;
  __syncthreads();
  for (int i = e0 + t; i < e1; i += 1024) {
    int pv = ebuck[i];
    int pos = atomicAdd(&lcur[pv & (NBSZ - 1)], 1);
    epack[pos] = ((unsigned)pv) >> NBBITS;  // src only
  }
}

// ---------- W1 prep: fp32 -> hi/lo bf16 in MFMA fragment order ----------
// elem (s,ct,lane,j) = W[k][col], k = s*32+(lane>>4)*8+j, col = ct*16+(lane&15)

__global__ void wprep_kernel(const float* __restrict__ W, unsigned short* __restrict__ Dh,
                             unsigned short* __restrict__ Dl) {
  int idx = blockIdx.x * 256 + threadIdx.x;
  int j = idx & 7, lane = (idx >> 3) & 63, ct = (idx >> 9) & 3, s = idx >> 11;
  int k = s * 32 + ((lane >> 4) << 3) + j;
  int col = ct * 16 + (lane & 15);
  float f = W[k * HID + col];
  unsigned short h = f2bf(f);
  Dh[idx] = h;
  Dl[idx] = f2bf(f - bf2f(h));
}

// ---------- split-bf16 MFMA GEMM: out_bf16[N,64] = dinv[row] * (x[N,K] @ W[K,64]) ----------

template <int K>
__global__ __launch_bounds__(256, 4) void gemm_mfma_kernel(
    const float* __restrict__ x, const unsigned short* __restrict__ Wh,
    const unsigned short* __restrict__ Wl, const float* __restrict__ dinv,
    unsigned short* __restrict__ out, int N) {
  constexpr int NS = K / 32;
  __shared__ float xs[2][64 * 32];
  const int t = threadIdx.x, lane = t & 63, w = t >> 6;
  const int g = lane >> 4, r15 = lane & 15;
  const int row0 = blockIdx.x * 64;
  const int arow = w * 16 + r15;
  f32x4 acc[4];
#pragma unroll
  for (int ct = 0; ct < 4; ++ct) acc[ct] = (f32x4){0.f, 0.f, 0.f, 0.f};

  auto stage = [&](int buf, int s) {
#pragma unroll
    for (int c = 0; c < 2; ++c) {
      int idx = c * 256 + t;
      int row = idx >> 3, gp = idx & 7;
      int gs = gp ^ (row & 7);
      int grow = min(row0 + row, N - 1);
      gld_lds16(x + (size_t)grow * K + s * 32 + gs * 4, &xs[buf][idx * 4]);
    }
  };
  stage(0, 0);
  for (int s = 0; s < NS; ++s) {
    __syncthreads();
    if (s + 1 < NS) stage((s + 1) & 1, s + 1);
    const float* xb = &xs[s & 1][arow * 32];
    float4 xv0 = *(const float4*)&xb[((2 * g) ^ (arow & 7)) * 4];
    float4 xv1 = *(const float4*)&xb[((2 * g + 1) ^ (arow & 7)) * 4];
    float xf[8] = {xv0.x, xv0.y, xv0.z, xv0.w, xv1.x, xv1.y, xv1.z, xv1.w};
    s16x8 xh, xl;
#pragma unroll
    for (int j = 0; j < 8; ++j) {
      unsigned short hb = f2bf(xf[j]);
      xh[j] = (short)hb;
      xl[j] = (short)f2bf(xf[j] - bf2f(hb));
    }
#pragma unroll
    for (int ct = 0; ct < 4; ++ct) {
      size_t o = (((size_t)(s * 4 + ct)) * 64 + lane) * 8;
      s16x8 wh = *(const s16x8*)&Wh[o];
      s16x8 wl = *(const s16x8*)&Wl[o];
      acc[ct] = __builtin_amdgcn_mfma_f32_16x16x32_bf16(wh, xh, acc[ct], 0, 0, 0);
      acc[ct] = __builtin_amdgcn_mfma_f32_16x16x32_bf16(wl, xh, acc[ct], 0, 0, 0);
      acc[ct] = __builtin_amdgcn_mfma_f32_16x16x32_bf16(wh, xl, acc[ct], 0, 0, 0);
    }
  }
  int row = row0 + arow;
  if (row < N) {
    float di = dinv[row];
    unsigned short* orow = out + (size_t)row * HID;
#pragma unroll
    for (int ct = 0; ct < 4; ++ct) {
      unsigned p0 = (unsigned)f2bf(di * acc[ct][0]) | ((unsigned)f2bf(di * acc[ct][1]) << 16);
      unsigned p1 = (unsigned)f2bf(di * acc[ct][2]) | ((unsigned)f2bf(di * acc[ct][3]) << 16);
      *(uint2*)&orow[ct * 16 + g * 4] = make_uint2(p0, p1);
    }
  }
}

// ---------- fused agg + relu + L2norm + next-layer 64x64 GEMM ----------
// hin holds hs = dinv*h (prescaled bf16). Per node:
//   v = l2norm(relu(dinv[d]*(hs[d] + sum_e hs[src_e]) + b))
//   hout[d] = bf16(dinv[d] * (v @ Wn))    (prescaled input for next agg)
// 16 nodes/block (4/wave, 16 lanes/node). Wn (16KB fp32) staged via
// global_load_lds at entry; latency hides under the agg gather loop.

__global__ __launch_bounds__(256) void agg_gemm_kernel(
    const int* __restrict__ rowptr, const int* __restrict__ ep,
    const float* __restrict__ dinv, const uint2* __restrict__ hin,
    const float* __restrict__ bias, const float* __restrict__ Wn,
    unsigned short* __restrict__ hout, int N) {
  __shared__ float Ws[64 * 64];      // [k][col] fp32, 16KB
  __shared__ float vrow[16 * 65];    // padded rows: bank = (lr*65+f)%32 varies with lr
  const int t = threadIdx.x;
#pragma unroll
  for (int c = 0; c < 4; ++c) {      // stage Wn -> LDS (linear, wave-uniform+lane*16)
    int idx = c * 256 + t;
    gld_lds16(Wn + idx * 4, &Ws[idx * 4]);
  }
  const int w = t >> 6, lane = t & 63;
  const int q = lane >> 4, sub = lane & 15;
  const int lr = w * 4 + q;
  const int node = blockIdx.x * 16 + lr;
  const bool act = node < N;
  float di = 0.f;
  if (act) {
    int beg = rowptr[node];
    int end = rowptr[node + 1];
    uint2 su = hin[(size_t)node * 16 + sub];  // self term
    float a0 = bf_lo(su.x), a1 = bf_hi(su.x), a2 = bf_lo(su.y), a3 = bf_hi(su.y);
    int j = beg;
    for (; j + 8 <= end; j += 8) {
      int e[8];
      uint2 hv[8];
#pragma unroll
      for (int u = 0; u < 8; ++u) e[u] = ep[j + u];
#pragma unroll
      for (int u = 0; u < 8; ++u) hv[u] = hin[(size_t)e[u] * 16 + sub];
#pragma unroll
      for (int u = 0; u < 8; ++u) {
        a0 += bf_lo(hv[u].x); a1 += bf_hi(hv[u].x);
        a2 += bf_lo(hv[u].y); a3 += bf_hi(hv[u].y);
      }
    }
    for (; j < end; ++j) {
      uint2 hu = hin[(size_t)ep[j] * 16 + sub];
      a0 += bf_lo(hu.x); a1 += bf_hi(hu.x); a2 += bf_lo(hu.y); a3 += bf_hi(hu.y);
    }
    di = dinv[node];
    float4 b4 = *(const float4*)&bias[sub * 4];
    float4 v;
    v.x = fmaxf(fmaf(di, a0, b4.x), 0.f);
    v.y = fmaxf(fmaf(di, a1, b4.y), 0.f);
    v.z = fmaxf(fmaf(di, a2, b4.z), 0.f);
    v.w = fmaxf(fmaf(di, a3, b4.w), 0.f);
    float ss = v.x * v.x + v.y * v.y + v.z * v.z + v.w * v.w;
#pragma unroll
    for (int off = 8; off; off >>= 1) ss += __shfl_xor(ss, off, 64);  // 16-lane quarter
    float inv = 1.f / fmaxf(sqrtf(ss), 1e-12f);
    v.x *= inv; v.y *= inv; v.z *= inv; v.w *= inv;
    *(float4*)&vrow[lr * 65 + sub * 4] = v;
  }
  __syncthreads();  // drains Wn staging (vmcnt) + vrow writes (lgkmcnt)
  if (act) {
    float4 o = make_float4(0.f, 0.f, 0.f, 0.f);
#pragma unroll 8
    for (int f = 0; f < 64; ++f) {
      float vf = vrow[lr * 65 + f];                       // quarter-broadcast
      float4 wf = *(const float4*)&Ws[f * 64 + sub * 4];  // 2-way (free)
      o.x = fmaf(vf, wf.x, o.x);
      o.y = fmaf(vf, wf.y, o.y);
      o.z = fmaf(vf, wf.z, o.z);
      o.w = fmaf(vf, wf.w, o.w);
    }
    unsigned p0 = (unsigned)f2bf(di * o.x) | ((unsigned)f2bf(di * o.y) << 16);
    unsigned p1 = (unsigned)f2bf(di * o.z) | ((unsigned)f2bf(di * o.w) << 16);
    *(uint2*)&hout[(size_t)node * HID + sub * 4] = make_uint2(p0, p1);
  }
}

// ---------- plain aggregation (final layer: bias only, fp32 out) ----------

template <bool RELU_NORM>
__global__ void agg_kernel(const int* __restrict__ rowptr, const int* __restrict__ ep,
                           const float* __restrict__ dinv, const uint2* __restrict__ h64,
                           const float* __restrict__ bias, float* __restrict__ out, int N) {
  int grp = (blockIdx.x * blockDim.x + threadIdx.x) >> 6;
  int lane = threadIdx.x & 63;
  int q = lane >> 4;
  int sub = lane & 15;
  int node = grp * 4 + q;
  if (node >= N) return;
  int beg = rowptr[node];
  int end = rowptr[node + 1];
  uint2 su = h64[(size_t)node * 16 + sub];
  float a0 = bf_lo(su.x), a1 = bf_hi(su.x), a2 = bf_lo(su.y), a3 = bf_hi(su.y);
  int j = beg;
  for (; j + 8 <= end; j += 8) {
    int e[8];
    uint2 hv[8];
#pragma unroll
    for (int u = 0; u < 8; ++u) e[u] = ep[j + u];
#pragma unroll
    for (int u = 0; u < 8; ++u) hv[u] = h64[(size_t)e[u] * 16 + sub];
#pragma unroll
    for (int u = 0; u < 8; ++u) {
      a0 += bf_lo(hv[u].x); a1 += bf_hi(hv[u].x);
      a2 += bf_lo(hv[u].y); a3 += bf_hi(hv[u].y);
    }
  }
  for (; j < end; ++j) {
    uint2 hu = h64[(size_t)ep[j] * 16 + sub];
    a0 += bf_lo(hu.x); a1 += bf_hi(hu.x); a2 += bf_lo(hu.y); a3 += bf_hi(hu.y);
  }
  float di = dinv[node];
  float4 b4 = *(const float4*)&bias[sub * 4];
  float4 v;
  v.x = fmaf(di, a0, b4.x); v.y = fmaf(di, a1, b4.y);
  v.z = fmaf(di, a2, b4.z); v.w = fmaf(di, a3, b4.w);
  if (RELU_NORM) {
    v.x = fmaxf(v.x, 0.f); v.y = fmaxf(v.y, 0.f);
    v.z = fmaxf(v.z, 0.f); v.w = fmaxf(v.w, 0.f);
    float ss = v.x * v.x + v.y * v.y + v.z * v.z + v.w * v.w;
#pragma unroll
    for (int off = 8; off; off >>= 1) ss += __shfl_xor(ss, off, 64);
    float inv = 1.f / fmaxf(sqrtf(ss), 1e-12f);
    v.x *= inv; v.y *= inv; v.z *= inv; v.w *= inv;
  }
  *(float4*)&out[(size_t)node * HID + sub * 4] = v;
}

// ---------- vector GEMM (fallback path only) ----------

template <int K, typename OT>
__global__ __launch_bounds__(256, 4) void gemm_kernel(const float* __restrict__ x,
                                                      const float* __restrict__ W,
                                                      OT* __restrict__ out, int N) {
  __shared__ float Xs[64 * KT];
  __shared__ float Ws[KT * 64];
  const int t = threadIdx.x;
  const int lane = t & 63;
  const int w = t >> 6;
  const int rg = lane >> 4;
  const int cg = lane & 15;
  const int row0 = blockIdx.x * 64;
  float4 acc[4];
#pragma unroll
  for (int r = 0; r < 4; ++r) acc[r] = make_float4(0.f, 0.f, 0.f, 0.f);

  for (int k0 = 0; k0 < K; k0 += KT) {
    if (k0) __syncthreads();
    const float* Wg = W + (size_t)k0 * HID;
#pragma unroll
    for (int c = 0; c < 4; ++c) {
      int idx = c * 256 + t;
      gld_lds16(Wg + idx * 4, &Ws[idx * 4]);
      int srow = idx >> 4;
      int sg = (idx & 15) ^ ((srow >> 2) & 3);
      int grow = min(row0 + srow, N - 1);
      gld_lds16(x + (size_t)grow * K + k0 + (sg << 2), &Xs[idx * 4]);
    }
    __syncthreads();
    const int rbase = w * 16 + rg * 4;
#pragma unroll 4
    for (int kb = 0; kb < KT / 4; ++kb) {
      float4 wq0 = *(const float4*)&Ws[(4 * kb + 0) * HID + cg * 4];
      float4 wq1 = *(const float4*)&Ws[(4 * kb + 1) * HID + cg * 4];
      float4 wq2 = *(const float4*)&Ws[(4 * kb + 2) * HID + cg * 4];
      float4 wq3 = *(const float4*)&Ws[(4 * kb + 3) * HID + cg * 4];
      const int sg = (kb ^ rg) << 2;
#pragma unroll
      for (int r = 0; r < 4; ++r) {
        float4 xv = *(const float4*)&Xs[(rbase + r) * KT + sg];
        acc[r].x = fmaf(xv.w, wq3.x, fmaf(xv.z, wq2.x, fmaf(xv.y, wq1.x, fmaf(xv.x, wq0.x, acc[r].x))));
        acc[r].y = fmaf(xv.w, wq3.y, fmaf(xv.z, wq2.y, fmaf(xv.y, wq1.y, fmaf(xv.x, wq0.y, acc[r].y))));
        acc[r].z = fmaf(xv.w, wq3.z, fmaf(xv.z, wq2.z, fmaf(xv.y, wq1.z, fmaf(xv.x, wq0.z, acc[r].z))));
        acc[r].w = fmaf(xv.w, wq3.w, fmaf(xv.z, wq2.w, fmaf(xv.y, wq1.w, fmaf(xv.x, wq0.w, acc[r].w))));
      }
    }
  }
#pragma unroll
  for (int r = 0; r < 4; ++r) {
    int row = row0 + w * 16 + rg * 4 + r;
    if (row < N) {
      OT* o = out + (size_t)row * HID + cg * 4;
      o[0] = (OT)acc[r].x; o[1] = (OT)acc[r].y; o[2] = (OT)acc[r].z; o[3] = (OT)acc[r].w;
    }
  }
}

// ---------- atomic fallback path ----------

__global__ void init_agg_kernel(const float* __restrict__ dinv, const float* __restrict__ h,
                                const float* __restrict__ bias, float* __restrict__ out, int N) {
  int t = blockIdx.x * blockDim.x + threadIdx.x;
  int i = t >> 6, f = t & 63;
  if (i >= N) return;
  float di = dinv[i];
  out[t] = di * di * h[t] + bias[f];
}

__global__ void edge_atomic_kernel(const int* __restrict__ src, const int* __restrict__ dst,
                                   const float* __restrict__ dinv, const float* __restrict__ h,
                                   float* __restrict__ out, int E) {
  int t = blockIdx.x * blockDim.x + threadIdx.x;
  int e = t >> 6;
  if (e >= E) return;
  int f = t & 63;
  int s = src[e], d = dst[e];
  atomicAdd(&out[(size_t)d * HID + f], dinv[s] * dinv[d] * h[(size_t)s * HID + f]);
}

__global__ void relu_norm_kernel(float* __restrict__ hbuf, int N) {
  int t = blockIdx.x * blockDim.x + threadIdx.x;
  int i = t >> 6;
  if (i >= N) return;
  float v = fmaxf(hbuf[t], 0.f);
  float ss = v * v;
#pragma unroll
  for (int off = 32; off; off >>= 1) ss += __shfl_xor(ss, off, 64);
  hbuf[t] = v / fmaxf(sqrtf(ss), 1e-12f);
}

// ---------- host ----------

extern "C" void kernel_launch(void* const* d_in, const int* in_sizes, int n_in,
                              void* d_out, int out_size, void* d_ws, size_t ws_size,
                              hipStream_t stream) {
  const float* x  = (const float*)d_in[0];
  const int*   ei = (const int*)d_in[1];
  const float* W1 = (const float*)d_in[2];
  const float* b1 = (const float*)d_in[3];
  const float* W2 = (const float*)d_in[4];
  const float* b2 = (const float*)d_in[5];
  const float* W3 = (const float*)d_in[6];
  const float* b3 = (const float*)d_in[7];
  float* out = (float*)d_out;

  const int IN = in_sizes[2] / HID;   // 256
  const int N  = in_sizes[0] / IN;    // 100000
  const int E  = in_sizes[1] / 2;     // 1600000
  const int* srcI = ei;
  const int* dstI = ei + E;
  const int B = (N + NBSZ - 1) >> NBBITS;

  char* w = (char*)d_ws;
  size_t off = 0;
  auto alloc = [&](size_t bytes) { void* p = w + off; off = align256(off + bytes); return p; };
  float* A      = (float*)alloc((size_t)N * HID * 4);  // fallback fp32 / {hsA,hsB} bf16 / ebuck
  float* dinv   = (float*)alloc((size_t)N * 4);
  int*   cnt    = (int*)alloc((size_t)N * 4);          // fallback only
  size_t base_need = off;
  int*   rowptr = (int*)alloc((size_t)(N + 1) * 4);
  int*   epack  = (int*)alloc((size_t)E * 4);          // src-only CSR payload
  int*   bbase  = (int*)alloc(1032 * 4);
  int*   gcur   = (int*)alloc(1024 * 4);
  int*   bcnt   = (int*)alloc(1024 * 4);
  unsigned short* W1h = (unsigned short*)alloc(16384 * 2);
  unsigned short* W1l = (unsigned short*)alloc(16384 * 2);
  size_t csr_need = off;

  if (base_need > ws_size) return;
  const bool use_csr = (csr_need <= ws_size) && (B <= P1_BMAX) &&
                       ((size_t)E <= (size_t)N * HID) && (N <= (1 << 20));
  unsigned short* hsA = (unsigned short*)A;            // N*64 bf16 = 12.8MB
  unsigned short* hsB = hsA + (size_t)N * HID;         // second half of A
  int* ebuck = (int*)A;  // pass-1 output lives in A until gemm1 overwrites it

  const int blkE    = (E + 255) / 256;
  const int blkN    = (N + 255) / 256;
  const int blkRow  = (N + 63) / 64;
  const int blkWave = (N * 64 + 255) / 256;
  const int blkAgg  = ((size_t)((N + 3) / 4) * 64 + 255) / 256;
  const int blkFuse = (N + 15) / 16;
  const int blkEF   = ((size_t)E * 64 + 255) / 256;
  const int blkBkt  = (E + P1_CH - 1) / P1_CH;

  if (use_csr) {
    hipMemsetAsync(bcnt, 0, 1024 * 4, stream);
    wprep_kernel<<<64, 256, 0, stream>>>(W1, W1h, W1l);
    bucket_count_kernel<<<256, 256, 0, stream>>>(dstI, bcnt, E, B);
    bucket_scan_kernel<<<1, 1024, 0, stream>>>(bcnt, bbase, gcur, B);
    bucketize_kernel<<<blkBkt, 256, 0, stream>>>(srcI, dstI, gcur, ebuck, E);
    bucket_sort_kernel<<<B, 1024, 0, stream>>>(ebuck, bbase, rowptr, epack, dinv, N, B, E);

    gemm_mfma_kernel<256><<<blkRow, 256, 0, stream>>>(x, W1h, W1l, dinv, hsA, N);
    agg_gemm_kernel<<<blkFuse, 256, 0, stream>>>(rowptr, epack, dinv, (const uint2*)hsA,
                                                 b1, W2, hsB, N);
    agg_gemm_kernel<<<blkFuse, 256, 0, stream>>>(rowptr, epack, dinv, (const uint2*)hsB,
                                                 b2, W3, hsA, N);
    agg_kernel<false><<<blkAgg, 256, 0, stream>>>(rowptr, epack, dinv, (const uint2*)hsA,
                                                  b3, out, N);
  } else {
    hipMemsetAsync(cnt, 0, (size_t)N * 4, stream);
    count_dst_kernel<<<blkE, 256, 0, stream>>>(dstI, cnt, E);
    dinv_kernel<<<blkN, 256, 0, stream>>>(cnt, dinv, N);

    gemm_kernel<256><<<blkRow, 256, 0, stream>>>(x, W1, A, N);
    init_agg_kernel<<<blkWave, 256, 0, stream>>>(dinv, A, b1, out, N);
    edge_atomic_kernel<<<blkEF, 256, 0, stream>>>(srcI, dstI, dinv, A, out, E);
    relu_norm_kernel<<<blkWave, 256, 0, stream>>>(out, N);

    gemm_kernel<64><<<blkRow, 256, 0, stream>>>(out, W2, A, N);
    init_agg_kernel<<<blkWave, 256, 0, stream>>>(dinv, A, b2, out, N);
    edge_atomic_kernel<<<blkEF, 256, 0, stream>>>(srcI, dstI, dinv, A, out, E);
    relu_norm_kernel<<<blkWave, 256, 0, stream>>>(out, N);

    gemm_kernel<64><<<blkRow, 256, 0, stream>>>(out, W3, A, N);
    init_agg_kernel<<<blkWave, 256, 0, stream>>>(dinv, A, b3, out, N);
    edge_atomic_kernel<<<blkEF, 256, 0, stream>>>(srcI, dstI, dinv, A, out, E);
  }
}